// Round 21
// baseline (321.309 us; speedup 1.0000x reference)
//
#include <hip/hip_runtime.h>

// LinearShift: out = round_to_fixed(x) @ v.T + round_to_fixed(bias)
// f16 MFMA GEMM, fp32 accum: absmax 0.0 validated (r7,r10,r11,r13,r16,r17/r20).
// ROUND 21: r17 + T5 setprio around MFMA clusters (ONLY change).
// r17's single-barrier/tile structure gives wave role-diversity (waves drift
// within the 12-read + 4-stage + 32-MFMA region); T5's catalog A/B (m218b:
// +21-25%, m224: +34-39%) says setprio converts that diversity into
// read||MFMA overlap via CU wave arbitration -- the overlap rounds 12-17
// failed to get from static instruction ordering. r10's setprio-null was the
// lockstep (m190) regime; this is the first role-diverse + setprio combo.

typedef _Float16 half8 __attribute__((ext_vector_type(8)));
typedef _Float16 half4v __attribute__((ext_vector_type(4)));
typedef float floatx4 __attribute__((ext_vector_type(4)));

__device__ __forceinline__ float qfix(float x) {
    float r = floorf(x * 256.0f + 0.5f);
    r = fminf(fmaxf(r, -32768.0f), 32767.0f);
    return r * 0.00390625f;
}

__global__ __launch_bounds__(256) void quantize_x_kernel(
        const float* __restrict__ x, _Float16* __restrict__ xq, int n4) {
    int i = blockIdx.x * 256 + threadIdx.x;
    const int stride = gridDim.x * 256;
    for (; i < n4; i += stride) {
        float4 v = reinterpret_cast<const float4*>(x)[i];
        half4v o;
        o[0] = (_Float16)qfix(v.x);
        o[1] = (_Float16)qfix(v.y);
        o[2] = (_Float16)qfix(v.z);
        o[3] = (_Float16)qfix(v.w);
        reinterpret_cast<half4v*>(xq)[i] = o;
    }
}

__global__ __launch_bounds__(256) void make_v_kernel(
        const float* __restrict__ shift, const float* __restrict__ sign,
        _Float16* __restrict__ v, int n4) {
    int i = blockIdx.x * 256 + threadIdx.x;
    const int stride = gridDim.x * 256;
    for (; i < n4; i += stride) {
        float4 sh = reinterpret_cast<const float4*>(shift)[i];
        float4 sg = reinterpret_cast<const float4*>(sign)[i];
        half4v o;
        o[0] = (_Float16)ldexpf((rintf(sg.x) == 0.0f) ? 1.0f : -1.0f, (int)rintf(sh.x));
        o[1] = (_Float16)ldexpf((rintf(sg.y) == 0.0f) ? 1.0f : -1.0f, (int)rintf(sh.y));
        o[2] = (_Float16)ldexpf((rintf(sg.z) == 0.0f) ? 1.0f : -1.0f, (int)rintf(sh.z));
        o[3] = (_Float16)ldexpf((rintf(sg.w) == 0.0f) ? 1.0f : -1.0f, (int)rintf(sh.w));
        reinterpret_cast<half4v*>(v)[i] = o;
    }
}

__device__ __forceinline__ void async_load16(const void* g, void* l) {
    __builtin_amdgcn_global_load_lds(
        (const __attribute__((address_space(1))) unsigned int*)g,
        (__attribute__((address_space(3))) unsigned int*)l,
        16, 0, 0);
}

// r15/r16-validated staging: LDS[r][b] = G[row0+r][k0 + (b ^ ((r>>1)&3))*8].
#define STAGE(P, DST) async_load16((P), (DST) + t * 8)
#define STAGE_TILE(NS)  do {                                              \
    STAGE(pA0, (NS));            STAGE(pB0, (NS) + 8192);                 \
    STAGE(pB1, (NS) + 12288);    STAGE(pA1, (NS) + 4096);                 \
    pA0 += 32; pA1 += 32; pB0 += 32; pB1 += 32; } while (0)

#define VM4()  asm volatile("s_waitcnt vmcnt(4)" ::: "memory")
#define VM0()  asm volatile("s_waitcnt vmcnt(0)" ::: "memory")
#define VM8()  asm volatile("s_waitcnt vmcnt(8)" ::: "memory")
#define BAR()  do { asm volatile("" ::: "memory");                        \
                    __builtin_amdgcn_s_barrier();                         \
                    asm volatile("" ::: "memory"); } while (0)

// Fragment reads (r16-validated addressing).
#define READ_AFQ(DST, SB, Q)                                              \
    _Pragma("unroll")                                                     \
    for (int mf = 0; mf < 4; ++mf)                                        \
      DST[mf] = *reinterpret_cast<const half8*>(                          \
          aRow + (SB) + (Q) * 8192 + mf * 1024);

#define READ_BF4(DST, SB)                                                 \
    do {                                                                  \
      DST[0] = *reinterpret_cast<const half8*>(bR0 + (SB));               \
      DST[1] = *reinterpret_cast<const half8*>(bR1 + (SB));               \
      DST[2] = *reinterpret_cast<const half8*>(bR0 + (SB) + 8192);        \
      DST[3] = *reinterpret_cast<const half8*>(bR1 + (SB) + 8192);        \
    } while (0)

// T5: setprio-wrapped MFMA cluster (the round-21 change).
#define MFMA16(QM, AF, BF)                                                \
    __builtin_amdgcn_s_setprio(1);                                        \
    _Pragma("unroll")                                                     \
    for (int qn = 0; qn < 2; ++qn)                                        \
      _Pragma("unroll")                                                   \
      for (int mf = 0; mf < 4; ++mf)                                      \
        _Pragma("unroll")                                                 \
        for (int nf = 0; nf < 2; ++nf)                                    \
          acc[QM][qn][mf][nf] = __builtin_amdgcn_mfma_f32_16x16x32_f16(   \
              AF[mf], BF[qn * 2 + nf], acc[QM][qn][mf][nf], 0, 0, 0);     \
    __builtin_amdgcn_s_setprio(0);

// LDS (dynamic, 128KB): 4 slots x [A0,A1,B0,B1][128][32] f16 (32KB/slot).
__global__ __launch_bounds__(512, 2) void gemm8_kernel(
        const _Float16* __restrict__ A,   // M x K
        const _Float16* __restrict__ B,   // N x K
        const float* __restrict__ bias,   // N
        float* __restrict__ C,            // M x N
        int M, int N, int K) {
    extern __shared__ _Float16 smem[];
    const int t = threadIdx.x;
    const int lane = t & 63;
    const int w = t >> 6;
    const int wrow = w >> 2;   // 0..1
    const int wcol = w & 3;    // 0..3
    const int fr  = lane & 15;
    const int kb  = lane >> 4; // 0..3

    // T1: bijective XCD swizzle (nwg % 8 == 0 for this shape)
    const int nwg = gridDim.x;
    const int bid = blockIdx.x;
    const int cpx = nwg >> 3;
    const int swz = (bid & 7) * cpx + (bid >> 3);
    const int ntN = N >> 8;
    const int bm = (swz / ntN) << 8;
    const int bn = (swz % ntN) << 8;

    // Running global stage pointers (+32 els/tile), r15-validated.
    const int r0  = t >> 2;
    const int cbo = ((t & 3) ^ ((t >> 3) & 3)) * 8;
    const _Float16* pA0 = A + (size_t)(bm +       r0) * K + cbo;
    const _Float16* pA1 = A + (size_t)(bm + 128 + r0) * K + cbo;
    const _Float16* pB0 = B + (size_t)(bn +       r0) * K + cbo;
    const _Float16* pB1 = B + (size_t)(bn + 128 + r0) * K + cbo;

    // Precomputed swizzled LDS read bases (bytes, slot 0), r15-validated.
    const int xk = ((kb ^ ((fr >> 1) & 3)) << 4);
    const char* sbase = (const char*)smem;
    const char* aRow = sbase + (wrow * 64 + fr) * 64 + xk;               // +q*8192 +mf*1024
    const char* bR0  = sbase + 16384 + (wcol * 32 +      fr) * 64 + xk;  // +qn*8192
    const char* bR1  = sbase + 16384 + (wcol * 32 + 16 + fr) * 64 + xk;

    // Prologue: stage tiles 0,1,2; retire tile 0; barrier; prime afA/bfC.
    STAGE_TILE(smem);
    STAGE_TILE(smem + 16384);
    STAGE_TILE(smem + 32768);
    VM8();
    BAR();

    half8 afA[4], afB[4], bfC[4], bfN[4];
    READ_AFQ(afA, 0, 0);      // af(0, q0)
    READ_BF4(bfC, 0);         // bf(0)

    floatx4 acc[2][2][4][2] = {};   // [qm][qn][mf][nf]
    const int NT = K >> 5;          // 128 (even)

    for (int T = 0; T < NT; T += 2) {
        // ---------- tile T (even): cur bf = bfC, next = bfN ----------
        {
            if (T < NT - 2) { VM4(); } else { VM0(); }   // retire tile T+1
            BAR();
            const int sb0 = (T & 3) << 15;
            const int sb1 = ((T + 1) & 3) << 15;
            READ_AFQ(afB, sb0, 1);        // af(T,q1)  -> consumed by MFMA acc1
            READ_BF4(bfN, sb1);           // bf(T+1)   -> consumed next tile
            MFMA16(0, afA, bfC);
            READ_AFQ(afA, sb1, 0);        // af(T+1,q0) -> consumed next tile
            if (T + 3 < NT) STAGE_TILE(smem + (((T + 3) & 3) << 14));
            MFMA16(1, afB, bfC);
        }
        // ---------- tile T+1 (odd): cur bf = bfN, next = bfC ----------
        {
            const int T1 = T + 1;
            if (T1 < NT - 2) { VM4(); } else if (T1 == NT - 2) { VM0(); }
            BAR();
            const int sb1 = (T1 & 3) << 15;
            const int sb2 = ((T1 + 1) & 3) << 15;
            READ_AFQ(afB, sb1, 1);        // af(T+1,q1)
            if (T1 + 1 < NT) READ_BF4(bfC, sb2);   // bf(T+2)
            MFMA16(0, afA, bfN);
            if (T1 + 1 < NT) READ_AFQ(afA, sb2, 0); // af(T+2,q0)
            if (T1 + 3 < NT) STAGE_TILE(smem + (((T1 + 3) & 3) << 14));
            MFMA16(1, afB, bfN);
        }
    }

    // Epilogue: C/D layout col=lane&15, row=(lane>>4)*4+reg (validated)
    #pragma unroll
    for (int qm = 0; qm < 2; ++qm)
      #pragma unroll
      for (int qn = 0; qn < 2; ++qn)
        #pragma unroll
        for (int nf = 0; nf < 2; ++nf) {
            const int gcol = bn + qn * 128 + wcol * 32 + nf * 16 + (lane & 15);
            const float bq = qfix(bias[gcol]);
            #pragma unroll
            for (int mf = 0; mf < 4; ++mf) {
                const int grow = bm + qm * 128 + wrow * 64 + mf * 16 + ((lane >> 4) << 2);
                float* p = C + (size_t)grow * N + gcol;
                #pragma unroll
                for (int r = 0; r < 4; ++r)
                    p[(size_t)r * N] = acc[qm][qn][mf][nf][r] + bq;
            }
        }
}

extern "C" void kernel_launch(void* const* d_in, const int* in_sizes, int n_in,
                              void* d_out, int out_size, void* d_ws, size_t ws_size,
                              hipStream_t stream) {
    const float* x     = (const float*)d_in[0];
    const float* shift = (const float*)d_in[1];
    const float* sign  = (const float*)d_in[2];
    const float* bias  = (const float*)d_in[3];
    float* out = (float*)d_out;

    const int N = in_sizes[3];            // 4096
    const int K = in_sizes[1] / N;        // 4096
    const int M = in_sizes[0] / K;        // 8192

    _Float16* xq = (_Float16*)d_ws;
    _Float16* v  = (_Float16*)((char*)d_ws + (size_t)M * K * sizeof(_Float16));

    quantize_x_kernel<<<2048, 256, 0, stream>>>(x, xq, M * K / 4);
    make_v_kernel<<<2048, 256, 0, stream>>>(shift, sign, v, N * K / 4);

    (void)hipFuncSetAttribute(reinterpret_cast<const void*>(gemm8_kernel),
                              hipFuncAttributeMaxDynamicSharedMemorySize, 131072);
    const int nblk = (M / 256) * (N / 256);
    gemm8_kernel<<<nblk, 512, 131072, stream>>>(xq, v, bias, out, M, N, K);
}

// Round 22
// 316.766 us; speedup vs baseline: 1.0143x; 1.0143x over previous
//
#include <hip/hip_runtime.h>

// LinearShift: out = round_to_fixed(x) @ v.T + round_to_fixed(bias)
// f16 MFMA GEMM, fp32 accum: absmax 0.0 validated (r7,r10,r11,r13,r16,r17,r20,r21).
// ROUND 22: r20 structure (4-slot BK=32 lookahead-3 fragment pipeline, NO
// setprio -- r21 A/B: setprio -4%). ONE change: vmcnt gates use
// __builtin_amdgcn_s_waitcnt(imm) instead of inline-asm text. Theory: asm
// blocks containing s_waitcnt text invalidate the compiler's lgkm tracking
// -> conservative lgkmcnt(0) before each MFMA cluster -> reads/MFMA strictly
// alternate (additive 1242+1156~2430 cyc/tile, identical across r10/r16/r17/
// r21). The builtin is visible to SIInsertWaitcnts: cross-region fragment
// reads get counted lgkm waits, reads drain under MFMA clusters.
// imm encoding (gfx9 family): vmcnt[3:0]|[15:14], expcnt[6:4]=7 (nowait),
// lgkmcnt[11:8]=15 (nowait): VM4=0x0F74, VM0=0x0F70, VM8=0x0F78.

typedef _Float16 half8 __attribute__((ext_vector_type(8)));
typedef _Float16 half4v __attribute__((ext_vector_type(4)));
typedef float floatx4 __attribute__((ext_vector_type(4)));

__device__ __forceinline__ float qfix(float x) {
    float r = floorf(x * 256.0f + 0.5f);
    r = fminf(fmaxf(r, -32768.0f), 32767.0f);
    return r * 0.00390625f;
}

__global__ __launch_bounds__(256) void quantize_x_kernel(
        const float* __restrict__ x, _Float16* __restrict__ xq, int n4) {
    int i = blockIdx.x * 256 + threadIdx.x;
    const int stride = gridDim.x * 256;
    for (; i < n4; i += stride) {
        float4 v = reinterpret_cast<const float4*>(x)[i];
        half4v o;
        o[0] = (_Float16)qfix(v.x);
        o[1] = (_Float16)qfix(v.y);
        o[2] = (_Float16)qfix(v.z);
        o[3] = (_Float16)qfix(v.w);
        reinterpret_cast<half4v*>(xq)[i] = o;
    }
}

__global__ __launch_bounds__(256) void make_v_kernel(
        const float* __restrict__ shift, const float* __restrict__ sign,
        _Float16* __restrict__ v, int n4) {
    int i = blockIdx.x * 256 + threadIdx.x;
    const int stride = gridDim.x * 256;
    for (; i < n4; i += stride) {
        float4 sh = reinterpret_cast<const float4*>(shift)[i];
        float4 sg = reinterpret_cast<const float4*>(sign)[i];
        half4v o;
        o[0] = (_Float16)ldexpf((rintf(sg.x) == 0.0f) ? 1.0f : -1.0f, (int)rintf(sh.x));
        o[1] = (_Float16)ldexpf((rintf(sg.y) == 0.0f) ? 1.0f : -1.0f, (int)rintf(sh.y));
        o[2] = (_Float16)ldexpf((rintf(sg.z) == 0.0f) ? 1.0f : -1.0f, (int)rintf(sh.z));
        o[3] = (_Float16)ldexpf((rintf(sg.w) == 0.0f) ? 1.0f : -1.0f, (int)rintf(sh.w));
        reinterpret_cast<half4v*>(v)[i] = o;
    }
}

__device__ __forceinline__ void async_load16(const void* g, void* l) {
    __builtin_amdgcn_global_load_lds(
        (const __attribute__((address_space(1))) unsigned int*)g,
        (__attribute__((address_space(3))) unsigned int*)l,
        16, 0, 0);
}

// r15/r16-validated staging: LDS[r][b] = G[row0+r][k0 + (b ^ ((r>>1)&3))*8].
#define STAGE(P, DST) async_load16((P), (DST) + t * 8)
#define STAGE_TILE(NS)  do {                                              \
    STAGE(pA0, (NS));            STAGE(pB0, (NS) + 8192);                 \
    STAGE(pB1, (NS) + 12288);    STAGE(pA1, (NS) + 4096);                 \
    pA0 += 32; pA1 += 32; pB0 += 32; pB1 += 32; } while (0)

// Waitcnt via builtin (visible to the compiler's waitcnt pass).
#define FENCE() asm volatile("" ::: "memory")
#define VM4()  do { FENCE(); __builtin_amdgcn_s_waitcnt(0x0F74); FENCE(); } while (0)
#define VM0()  do { FENCE(); __builtin_amdgcn_s_waitcnt(0x0F70); FENCE(); } while (0)
#define VM8()  do { FENCE(); __builtin_amdgcn_s_waitcnt(0x0F78); FENCE(); } while (0)
#define BAR()  do { FENCE(); __builtin_amdgcn_s_barrier(); FENCE(); } while (0)

// Fragment reads (r16-validated addressing).
#define READ_AFQ(DST, SB, Q)                                              \
    _Pragma("unroll")                                                     \
    for (int mf = 0; mf < 4; ++mf)                                        \
      DST[mf] = *reinterpret_cast<const half8*>(                          \
          aRow + (SB) + (Q) * 8192 + mf * 1024);

#define READ_BF4(DST, SB)                                                 \
    do {                                                                  \
      DST[0] = *reinterpret_cast<const half8*>(bR0 + (SB));               \
      DST[1] = *reinterpret_cast<const half8*>(bR1 + (SB));               \
      DST[2] = *reinterpret_cast<const half8*>(bR0 + (SB) + 8192);        \
      DST[3] = *reinterpret_cast<const half8*>(bR1 + (SB) + 8192);        \
    } while (0)

#define MFMA16(QM, AF, BF)                                                \
    _Pragma("unroll")                                                     \
    for (int qn = 0; qn < 2; ++qn)                                        \
      _Pragma("unroll")                                                   \
      for (int mf = 0; mf < 4; ++mf)                                      \
        _Pragma("unroll")                                                 \
        for (int nf = 0; nf < 2; ++nf)                                    \
          acc[QM][qn][mf][nf] = __builtin_amdgcn_mfma_f32_16x16x32_f16(   \
              AF[mf], BF[qn * 2 + nf], acc[QM][qn][mf][nf], 0, 0, 0);

// LDS (dynamic, 128KB): 4 slots x [A0,A1,B0,B1][128][32] f16 (32KB/slot).
__global__ __launch_bounds__(512, 2) void gemm8_kernel(
        const _Float16* __restrict__ A,   // M x K
        const _Float16* __restrict__ B,   // N x K
        const float* __restrict__ bias,   // N
        float* __restrict__ C,            // M x N
        int M, int N, int K) {
    extern __shared__ _Float16 smem[];
    const int t = threadIdx.x;
    const int lane = t & 63;
    const int w = t >> 6;
    const int wrow = w >> 2;   // 0..1
    const int wcol = w & 3;    // 0..3
    const int fr  = lane & 15;
    const int kb  = lane >> 4; // 0..3

    // T1: bijective XCD swizzle (nwg % 8 == 0 for this shape)
    const int nwg = gridDim.x;
    const int bid = blockIdx.x;
    const int cpx = nwg >> 3;
    const int swz = (bid & 7) * cpx + (bid >> 3);
    const int ntN = N >> 8;
    const int bm = (swz / ntN) << 8;
    const int bn = (swz % ntN) << 8;

    // Running global stage pointers (+32 els/tile), r15-validated.
    const int r0  = t >> 2;
    const int cbo = ((t & 3) ^ ((t >> 3) & 3)) * 8;
    const _Float16* pA0 = A + (size_t)(bm +       r0) * K + cbo;
    const _Float16* pA1 = A + (size_t)(bm + 128 + r0) * K + cbo;
    const _Float16* pB0 = B + (size_t)(bn +       r0) * K + cbo;
    const _Float16* pB1 = B + (size_t)(bn + 128 + r0) * K + cbo;

    // Precomputed swizzled LDS read bases (bytes, slot 0), r15-validated.
    const int xk = ((kb ^ ((fr >> 1) & 3)) << 4);
    const char* sbase = (const char*)smem;
    const char* aRow = sbase + (wrow * 64 + fr) * 64 + xk;               // +q*8192 +mf*1024
    const char* bR0  = sbase + 16384 + (wcol * 32 +      fr) * 64 + xk;  // +qn*8192
    const char* bR1  = sbase + 16384 + (wcol * 32 + 16 + fr) * 64 + xk;

    // Prologue: stage tiles 0,1,2; retire tile 0; barrier; prime afA/bfC.
    STAGE_TILE(smem);
    STAGE_TILE(smem + 16384);
    STAGE_TILE(smem + 32768);
    VM8();
    BAR();

    half8 afA[4], afB[4], bfC[4], bfN[4];
    READ_AFQ(afA, 0, 0);      // af(0, q0)
    READ_BF4(bfC, 0);         // bf(0)

    floatx4 acc[2][2][4][2] = {};   // [qm][qn][mf][nf]
    const int NT = K >> 5;          // 128 (even)

    for (int T = 0; T < NT; T += 2) {
        // ---------- tile T (even): cur bf = bfC, next = bfN ----------
        {
            if (T < NT - 2) { VM4(); } else { VM0(); }   // retire tile T+1
            BAR();
            const int sb0 = (T & 3) << 15;
            const int sb1 = ((T + 1) & 3) << 15;
            READ_AFQ(afB, sb0, 1);        // af(T,q1)  -> consumed by MFMA cluster 2
            READ_BF4(bfN, sb1);           // bf(T+1)   -> consumed next tile
            MFMA16(0, afA, bfC);
            READ_AFQ(afA, sb1, 0);        // af(T+1,q0) -> consumed next tile
            if (T + 3 < NT) STAGE_TILE(smem + (((T + 3) & 3) << 14));
            MFMA16(1, afB, bfC);
        }
        // ---------- tile T+1 (odd): cur bf = bfN, next = bfC ----------
        {
            const int T1 = T + 1;
            if (T1 < NT - 2) { VM4(); } else if (T1 == NT - 2) { VM0(); }
            BAR();
            const int sb1 = (T1 & 3) << 15;
            const int sb2 = ((T1 + 1) & 3) << 15;
            READ_AFQ(afB, sb1, 1);        // af(T+1,q1)
            if (T1 + 1 < NT) READ_BF4(bfC, sb2);   // bf(T+2)
            MFMA16(0, afA, bfN);
            if (T1 + 1 < NT) READ_AFQ(afA, sb2, 0); // af(T+2,q0)
            if (T1 + 3 < NT) STAGE_TILE(smem + (((T1 + 3) & 3) << 14));
            MFMA16(1, afB, bfN);
        }
    }

    // Epilogue: C/D layout col=lane&15, row=(lane>>4)*4+reg (validated)
    #pragma unroll
    for (int qm = 0; qm < 2; ++qm)
      #pragma unroll
      for (int qn = 0; qn < 2; ++qn)
        #pragma unroll
        for (int nf = 0; nf < 2; ++nf) {
            const int gcol = bn + qn * 128 + wcol * 32 + nf * 16 + (lane & 15);
            const float bq = qfix(bias[gcol]);
            #pragma unroll
            for (int mf = 0; mf < 4; ++mf) {
                const int grow = bm + qm * 128 + wrow * 64 + mf * 16 + ((lane >> 4) << 2);
                float* p = C + (size_t)grow * N + gcol;
                #pragma unroll
                for (int r = 0; r < 4; ++r)
                    p[(size_t)r * N] = acc[qm][qn][mf][nf][r] + bq;
            }
        }
}

extern "C" void kernel_launch(void* const* d_in, const int* in_sizes, int n_in,
                              void* d_out, int out_size, void* d_ws, size_t ws_size,
                              hipStream_t stream) {
    const float* x     = (const float*)d_in[0];
    const float* shift = (const float*)d_in[1];
    const float* sign  = (const float*)d_in[2];
    const float* bias  = (const float*)d_in[3];
    float* out = (float*)d_out;

    const int N = in_sizes[3];            // 4096
    const int K = in_sizes[1] / N;        // 4096
    const int M = in_sizes[0] / K;        // 8192

    _Float16* xq = (_Float16*)d_ws;
    _Float16* v  = (_Float16*)((char*)d_ws + (size_t)M * K * sizeof(_Float16));

    quantize_x_kernel<<<2048, 256, 0, stream>>>(x, xq, M * K / 4);
    make_v_kernel<<<2048, 256, 0, stream>>>(shift, sign, v, N * K / 4);

    (void)hipFuncSetAttribute(reinterpret_cast<const void*>(gemm8_kernel),
                              hipFuncAttributeMaxDynamicSharedMemorySize, 131072);
    const int nblk = (M / 256) * (N / 256);
    gemm8_kernel<<<nblk, 512, 131072, stream>>>(xq, v, bias, out, M, N, K);
}